// Round 2
// baseline (782.384 us; speedup 1.0000x reference)
//
#include <hip/hip_runtime.h>

#define N_NODES 100000
#define F 64
#define C 32
#define KH 3
#define E 1600000
#define NE (KH * E)  // 4,800,000 edges total

// ---------------------------------------------------------------------------
// K1: y[n, c] = sum_f x[n, f] * W[f, c]   (all fp32)
// One thread per node; W staged in LDS (8 KB).
// ---------------------------------------------------------------------------
__global__ __launch_bounds__(256) void gemm_xw(const float* __restrict__ x,
                                               const float* __restrict__ W,
                                               float* __restrict__ y) {
    __shared__ float Ws[F * C];  // 8 KB
    for (int i = threadIdx.x; i < F * C; i += 256) Ws[i] = W[i];
    __syncthreads();

    const int node = blockIdx.x * 256 + threadIdx.x;
    if (node >= N_NODES) return;

    const float4* xp = (const float4*)(x + (size_t)node * F);
    float acc[C];
#pragma unroll
    for (int c = 0; c < C; c++) acc[c] = 0.f;

#pragma unroll
    for (int i = 0; i < 16; i++) {          // 16 x float4 = 64 features
        float4 v = xp[i];
        const int f = i * 4;
#pragma unroll
        for (int c = 0; c < C; c++) {
            acc[c] += v.x * Ws[(f + 0) * C + c];
            acc[c] += v.y * Ws[(f + 1) * C + c];
            acc[c] += v.z * Ws[(f + 2) * C + c];
            acc[c] += v.w * Ws[(f + 3) * C + c];
        }
    }

    float4* yo = (float4*)(y + (size_t)node * C);
#pragma unroll
    for (int i = 0; i < 8; i++)
        yo[i] = make_float4(acc[4 * i], acc[4 * i + 1], acc[4 * i + 2], acc[4 * i + 3]);
}

// ---------------------------------------------------------------------------
// K2: per-row edge histogram. One thread per edge.
// ---------------------------------------------------------------------------
__global__ __launch_bounds__(256) void hist_k(const int* __restrict__ rows,
                                              int* __restrict__ counts) {
    const int e = blockIdx.x * 256 + threadIdx.x;
    if (e < NE) atomicAdd(&counts[rows[e]], 1);
}

// ---------------------------------------------------------------------------
// K3: bucket allocation. Per-wave inclusive scan of counts, one global
// atomicAdd per block to claim contiguous space. Bucket ordering across rows
// is irrelevant (we only need per-row contiguity), so no full prefix-sum.
// ---------------------------------------------------------------------------
__global__ __launch_bounds__(256) void alloc_k(const int* __restrict__ counts,
                                               int* __restrict__ start,
                                               int* __restrict__ cursor,
                                               int* __restrict__ gcursor) {
    __shared__ int wsum[4];
    __shared__ int wbase[4];
    __shared__ int blockbase;

    const int tid = threadIdx.x;
    const int lane = tid & 63;
    const int wid = tid >> 6;
    const int row = blockIdx.x * 256 + tid;

    const int cnt = (row < N_NODES) ? counts[row] : 0;
    int scan = cnt;  // inclusive wave scan (wave = 64 lanes)
#pragma unroll
    for (int d = 1; d < 64; d <<= 1) {
        int u = __shfl_up(scan, d);
        if (lane >= d) scan += u;
    }
    if (lane == 63) wsum[wid] = scan;
    __syncthreads();
    if (tid == 0) {
        int total = 0;
#pragma unroll
        for (int w = 0; w < 4; w++) { wbase[w] = total; total += wsum[w]; }
        blockbase = atomicAdd(gcursor, total);
    }
    __syncthreads();
    if (row < N_NODES) {
        const int st = blockbase + wbase[wid] + (scan - cnt);  // exclusive
        start[row] = st;
        cursor[row] = st;
    }
}

// ---------------------------------------------------------------------------
// K4: fill buckets. One thread per edge; claim a slot in the row's bucket and
// store packed {col, val*alpha[k]} (8 B).
// ---------------------------------------------------------------------------
__global__ __launch_bounds__(256) void bucket_k(const float* __restrict__ vals,
                                                const int* __restrict__ rows,
                                                const int* __restrict__ cols,
                                                const float* __restrict__ alpha,
                                                int* __restrict__ cursor,
                                                int2* __restrict__ edgebuf) {
    const int e = blockIdx.x * 256 + threadIdx.x;
    if (e >= NE) return;
    const int k = (e >= 2 * E) ? 2 : (e >= E) ? 1 : 0;
    const float w = vals[e] * alpha[k];
    const int pos = atomicAdd(&cursor[rows[e]], 1);
    edgebuf[pos] = make_int2(cols[e], __float_as_int(w));
}

// ---------------------------------------------------------------------------
// K5: gather-aggregate. 32 lanes per row (lane = channel). Walk the row's
// bucket sequentially: broadcast 8B bucket entry + coalesced 128B gather of
// y[col]. Accumulate in a register, write out exactly once. Bias fused.
// ---------------------------------------------------------------------------
__global__ __launch_bounds__(256) void gather_k(const int2* __restrict__ edgebuf,
                                                const int* __restrict__ start,
                                                const int* __restrict__ counts,
                                                const float* __restrict__ y,
                                                const float* __restrict__ bias,
                                                float* __restrict__ out) {
    const int t = blockIdx.x * 256 + threadIdx.x;
    const int row = t >> 5;
    const int c = t & 31;
    if (row >= N_NODES) return;

    const int s = start[row];
    const int n = counts[row];
    float acc = bias[c];

    int i = 0;
    for (; i + 4 <= n; i += 4) {  // 4 independent gathers in flight
        const int2 p0 = edgebuf[s + i + 0];
        const int2 p1 = edgebuf[s + i + 1];
        const int2 p2 = edgebuf[s + i + 2];
        const int2 p3 = edgebuf[s + i + 3];
        const float y0 = y[p0.x * C + c];
        const float y1 = y[p1.x * C + c];
        const float y2 = y[p2.x * C + c];
        const float y3 = y[p3.x * C + c];
        acc += __int_as_float(p0.y) * y0;
        acc += __int_as_float(p1.y) * y1;
        acc += __int_as_float(p2.y) * y2;
        acc += __int_as_float(p3.y) * y3;
    }
    for (; i < n; i++) {
        const int2 p = edgebuf[s + i];
        acc += __int_as_float(p.y) * y[p.x * C + c];
    }
    out[row * C + c] = acc;
}

// ---------------------------------------------------------------------------
// Fallback path (old kernels) if the workspace is too small for the CSR build.
// ---------------------------------------------------------------------------
__global__ __launch_bounds__(256) void scatter_edges(
    const float* __restrict__ vals, const int* __restrict__ rows,
    const int* __restrict__ cols, const float* __restrict__ alpha,
    const float* __restrict__ y, float* __restrict__ out_acc) {
    const int t = blockIdx.x * 256 + threadIdx.x;
    const int e = t >> 5;
    const int c = t & 31;
    if (e >= KH * E) return;
    const int k = (e >= 2 * E) ? 2 : (e >= E) ? 1 : 0;

    const float w = vals[e] * alpha[k];
    const int row = rows[e];
    const int col = cols[e];

    const float yv = y[(size_t)col * C + c];
    unsafeAtomicAdd(out_acc + (size_t)row * C + c, w * yv);
}

__global__ __launch_bounds__(256) void finalize_k(float* __restrict__ out,
                                                  const float* __restrict__ bias) {
    const int idx = (blockIdx.x * 256 + threadIdx.x) * 4;
    if (idx >= N_NODES * C) return;
    const int c0 = idx & (C - 1);
    float4 v = *(float4*)(out + idx);
    v.x += bias[c0 + 0];
    v.y += bias[c0 + 1];
    v.z += bias[c0 + 2];
    v.w += bias[c0 + 3];
    *(float4*)(out + idx) = v;
}

// ---------------------------------------------------------------------------
extern "C" void kernel_launch(void* const* d_in, const int* in_sizes, int n_in,
                              void* d_out, int out_size, void* d_ws, size_t ws_size,
                              hipStream_t stream) {
    const float* x         = (const float*)d_in[0];  // [N, F] fp32
    const float* edge_vals = (const float*)d_in[1];  // [K, E] fp32
    const float* W         = (const float*)d_in[2];  // [F, C] fp32
    const float* b         = (const float*)d_in[3];  // [C]    fp32
    const float* alpha     = (const float*)d_in[4];  // [K]    fp32
    const int*   edge_rows = (const int*)d_in[5];    // [K, E] int32
    const int*   edge_cols = (const int*)d_in[6];    // [K, E] int32
    float*       out       = (float*)d_out;          // [N, C] fp32

    // Workspace layout
    const size_t offY      = 0;                                  // 12.8 MB
    const size_t offEB     = (size_t)N_NODES * C * 4;            // 12,800,000 (8B aligned)
    const size_t offCounts = offEB + (size_t)NE * 8;             // 51,200,000
    const size_t offGcur   = offCounts + (size_t)N_NODES * 4;    // 51,600,000
    const size_t offStart  = offGcur + 256;                      // 51,600,256
    const size_t offCur    = offStart + (size_t)N_NODES * 4;     // 52,000,256
    const size_t need      = offCur + (size_t)N_NODES * 4;       // 52,400,256

    float* y = (float*)((char*)d_ws + offY);

    gemm_xw<<<(N_NODES + 255) / 256, 256, 0, stream>>>(x, W, y);

    if (ws_size >= need) {
        int2* edgebuf = (int2*)((char*)d_ws + offEB);
        int*  counts  = (int*)((char*)d_ws + offCounts);
        int*  gcursor = (int*)((char*)d_ws + offGcur);
        int*  start   = (int*)((char*)d_ws + offStart);
        int*  cursor  = (int*)((char*)d_ws + offCur);

        // zero counts + gcursor (contiguous)
        hipMemsetAsync(counts, 0, (size_t)N_NODES * 4 + 256, stream);

        const int eblocks = (NE + 255) / 256;  // 18750
        hist_k<<<eblocks, 256, 0, stream>>>(edge_rows, counts);
        alloc_k<<<(N_NODES + 255) / 256, 256, 0, stream>>>(counts, start, cursor, gcursor);
        bucket_k<<<eblocks, 256, 0, stream>>>(edge_vals, edge_rows, edge_cols,
                                              alpha, cursor, edgebuf);
        gather_k<<<(N_NODES * 32 + 255) / 256, 256, 0, stream>>>(
            edgebuf, start, counts, y, b, out);
    } else {
        // Fallback: atomic scatter path (needs only y in workspace)
        hipMemsetAsync(out, 0, (size_t)N_NODES * C * sizeof(float), stream);
        const long long scatter_threads = (long long)KH * E * C;  // 153.6M
        const int scatter_blocks = (int)((scatter_threads + 255) / 256);
        scatter_edges<<<scatter_blocks, 256, 0, stream>>>(
            edge_vals, edge_rows, edge_cols, alpha, y, out);
        finalize_k<<<(N_NODES * C / 4 + 255) / 256, 256, 0, stream>>>(out, b);
    }
}